// Round 3
// baseline (36229.346 us; speedup 1.0000x reference)
//
#include <hip/hip_runtime.h>
#include <hip/hip_bf16.h>

#define NB 16
#define NBLK 128
#define TT 512
#define DD 20

using bf16x8 = __attribute__((ext_vector_type(8))) short;
using f32x4  = __attribute__((ext_vector_type(4))) float;

// workspace byte offsets
#define OFF_WIH0  0          // 1024x20  -> 64 tiles x 1 kt  : 32768 bf16 = 65536 B
#define OFF_WHH0  65536      // 1024x256 -> 64 x 8           : 262144 bf16 = 524288 B
#define OFF_WIH1  589824
#define OFF_WHH1  1114112
#define OFF_WPROJ 1638400    // 20x256 -> 2 x 8              : 8192 bf16 = 16384 B
#define OFF_B0    1654784    // 1024 f32
#define OFF_B1    1658880    // 1024 f32

__device__ __forceinline__ float sigf(float x) { return 1.0f / (1.0f + __expf(-x)); }
__device__ __forceinline__ float tanhfast(float x) { return 1.0f - 2.0f / (__expf(2.0f * x) + 1.0f); }

// ---- prep: fp32 weights -> bf16, swizzled into MFMA B-fragment order ----
// B-frag for mfma_f32_16x16x32_bf16: lane L holds B[k = kt*32 + (L>>4)*8 + j][n = nt*16 + (L&15)], j=0..7
__global__ void prep_kernel(const float* __restrict__ wih0, const float* __restrict__ whh0,
                            const float* __restrict__ wih1, const float* __restrict__ whh1,
                            const float* __restrict__ wproj,
                            const float* __restrict__ bih0, const float* __restrict__ bhh0,
                            const float* __restrict__ bih1, const float* __restrict__ bhh1,
                            char* __restrict__ ws) {
    int idx = blockIdx.x * 256 + threadIdx.x;
    const float* src;
    __hip_bfloat16* dst;
    int e, N, K, nKt;
    if (idx < 32768)       { e = idx;          src = wih0;  N = 1024; K = 20;  nKt = 1; dst = (__hip_bfloat16*)(ws + OFF_WIH0); }
    else if (idx < 294912) { e = idx - 32768;  src = whh0;  N = 1024; K = 256; nKt = 8; dst = (__hip_bfloat16*)(ws + OFF_WHH0); }
    else if (idx < 557056) { e = idx - 294912; src = wih1;  N = 1024; K = 256; nKt = 8; dst = (__hip_bfloat16*)(ws + OFF_WIH1); }
    else if (idx < 819200) { e = idx - 557056; src = whh1;  N = 1024; K = 256; nKt = 8; dst = (__hip_bfloat16*)(ws + OFF_WHH1); }
    else if (idx < 827392) { e = idx - 819200; src = wproj; N = 20;   K = 256; nKt = 8; dst = (__hip_bfloat16*)(ws + OFF_WPROJ); }
    else if (idx < 828416) { int j = idx - 827392; ((float*)(ws + OFF_B0))[j] = bih0[j] + bhh0[j]; return; }
    else if (idx < 829440) { int j = idx - 828416; ((float*)(ws + OFF_B1))[j] = bih1[j] + bhh1[j]; return; }
    else return;
    int j    = e & 7;
    int lane = (e >> 3) & 63;
    int tile = e >> 9;
    int kt = tile % nKt;
    int nt = tile / nKt;
    int n = nt * 16 + (lane & 15);
    int k = kt * 32 + ((lane >> 4) << 3) + j;
    float v = (n < N && k < K) ? src[n * K + k] : 0.0f;
    dst[e] = __float2bfloat16(v);
}

// ---- persistent decoder: 128 blocks x 512 threads, 16 batch rows/block, 512 steps ----
__global__ __launch_bounds__(512, 1) void decoder_kernel(
    const float* __restrict__ z, const float* __restrict__ w_lh, const float* __restrict__ b_lh,
    const float* __restrict__ w_lc, const float* __restrict__ b_lc,
    const float* __restrict__ b_proj, const char* __restrict__ ws,
    float* __restrict__ out) {

    __shared__ __align__(16) __hip_bfloat16 h0b[2][16][264]; // +8 pad, rows 528 B
    __shared__ __align__(16) __hip_bfloat16 h1b[2][16][264];
    __shared__ __align__(16) __hip_bfloat16 xb[16][32];      // K padded 20->32 with zeros
    __shared__ __align__(16) __hip_bfloat16 wxs[32768];      // W_ih0, LDS-resident (64 KB)
    __shared__ __align__(16) __hip_bfloat16 wps[8192];       // W_proj, LDS-resident (16 KB)
    __shared__ float cinit[2][16][256];
    __shared__ float zb[16][32];

    const int tid = threadIdx.x;
    const int blk = blockIdx.x;
    const int b0  = blk * NB;

    // stage z, zero x0
    {
        int i = tid;
        zb[i >> 5][i & 31] = z[(b0 + (i >> 5)) * 32 + (i & 31)];
        xb[i >> 5][i & 31] = __float2bfloat16(0.0f);
    }
    // stage W_ih0 and W_proj into LDS (one-time)
    {
        const bf16x8* sx = (const bf16x8*)(ws + OFF_WIH0);
        bf16x8* dx = (bf16x8*)wxs;
        for (int i = tid; i < 4096; i += 512) dx[i] = sx[i];
        const bf16x8* sp = (const bf16x8*)(ws + OFF_WPROJ);
        bf16x8* dp = (bf16x8*)wps;
        for (int i = tid; i < 1024; i += 512) dp[i] = sp[i];
    }
    __syncthreads();

    // h/c init (fp32 VALU, K=32)
    for (int ii = 0; ii < 16; ii++) {
        int pi = ii * 512 + tid;
        int b = pi >> 9, col = pi & 511;
        float dh = b_lh[col], dc = b_lc[col];
        #pragma unroll 8
        for (int k = 0; k < 32; k++) {
            float zv = zb[b][k];
            dh += zv * w_lh[col * 32 + k];
            dc += zv * w_lc[col * 32 + k];
        }
        if (col < 256) { h0b[0][b][col]       = __float2bfloat16(dh); cinit[0][b][col]       = dc; }
        else           { h1b[0][b][col - 256] = __float2bfloat16(dh); cinit[1][b][col - 256] = dc; }
    }
    __syncthreads();

    const int wv = tid >> 6, ln = tid & 63;
    const int l15 = ln & 15, lq = ln >> 4;

    float c0r[2][4], c1r[2][4];
    #pragma unroll
    for (int h = 0; h < 2; h++)
        #pragma unroll
        for (int r = 0; r < 4; r++) {
            int u = wv * 32 + h * 16 + l15, b = lq * 4 + r;
            c0r[h][r] = cinit[0][b][u];
            c1r[h][r] = cinit[1][b][u];
        }

    const float* bias0 = (const float*)(ws + OFF_B0);
    const float* bias1 = (const float*)(ws + OFF_B1);
    float bs0[8], bs1[8];
    #pragma unroll
    for (int q = 0; q < 8; q++) {
        int col = (q >> 1) * 256 + wv * 32 + (q & 1) * 16 + l15;
        bs0[q] = bias0[col];
        bs1[q] = bias1[col];
    }
    const float bpj0 = b_proj[l15];
    const float bpj1 = (l15 < 4) ? b_proj[16 + l15] : 0.0f;

    int bo8[8], bo1[8];
    #pragma unroll
    for (int q = 0; q < 8; q++) {
        int tbq = (q >> 1) * 16 + wv * 2 + (q & 1);
        bo8[q] = tbq * 8192 + ln * 16;
        bo1[q] = tbq * 1024 + ln * 16;
    }

    const char* W0h = ws + OFF_WHH0;
    const char* W1x = ws + OFF_WIH1;
    const char* W1h = ws + OFF_WHH1;
    const char* wxs_c = (const char*)wxs;
    const char* wps_c = (const char*)wps;

    const char* hA = (const char*)&h0b[0][0][0];
    const char* hB = (const char*)&h1b[0][0][0];
    const int aoff = l15 * 528 + lq * 16;
    const char* xA = (const char*)&xb[0][0] + l15 * 64 + lq * 16;

    float* outp = out + (size_t)b0 * TT * DD;

    // phase C: emits y(t-1) -> out, x(t) -> xb. h1(t-1) lives in h1b[t&1]. Pure LDS.
    auto phaseC = [&](int t) {
        const int pp = t & 1;
        f32x4 py0 = {bpj0, bpj0, bpj0, bpj0};
        f32x4 py1 = {bpj1, bpj1, bpj1, bpj1};
        const char* baseh = hB + pp * 8448 + aoff;
        #pragma unroll
        for (int kt = 0; kt < 8; kt++) {
            bf16x8 ah  = *(const bf16x8*)(baseh + kt * 64);
            bf16x8 bf0 = *(const bf16x8*)(wps_c + kt * 1024 + ln * 16);
            bf16x8 bf1 = *(const bf16x8*)(wps_c + 8192 + kt * 1024 + ln * 16);
            py0 = __builtin_amdgcn_mfma_f32_16x16x32_bf16(ah, bf0, py0, 0, 0, 0);
            py1 = __builtin_amdgcn_mfma_f32_16x16x32_bf16(ah, bf1, py1, 0, 0, 0);
        }
        #pragma unroll
        for (int r = 0; r < 4; r++) {
            int b = lq * 4 + r;
            float y0 = py0[r];
            outp[(size_t)(b * TT + (t - 1)) * DD + l15] = y0;
            xb[b][l15] = __float2bfloat16(y0);
            if (l15 < 4) {
                float y1 = py1[r];
                outp[(size_t)(b * TT + (t - 1)) * DD + 16 + l15] = y1;
                xb[b][16 + l15] = __float2bfloat16(y1);
            }
        }
    };

    #pragma unroll 1
    for (int t = 0; t < TT; t++) {
        const int p = t & 1;

        // ---- phase C(t-1): wave 7 only, concurrent with A1 on other waves ----
        if (t > 0 && wv == 7) phaseC(t);

        // ---- A1: acc = bias0 + h0_old @ W0h^T  (depth-1 double-buffered prefetch) ----
        f32x4 acc[8];
        #pragma unroll
        for (int q = 0; q < 8; q++) { f32x4 v = {bs0[q], bs0[q], bs0[q], bs0[q]}; acc[q] = v; }
        {
            const char* baseA = hA + p * 8448 + aoff;
            bf16x8 af[8];
            #pragma unroll
            for (int kt = 0; kt < 8; kt++) af[kt] = *(const bf16x8*)(baseA + kt * 64);
            bf16x8 wb[2][8];
            #pragma unroll
            for (int q = 0; q < 8; q++) wb[0][q] = *(const bf16x8*)(W0h + bo8[q]);
            #pragma unroll
            for (int kt = 0; kt < 8; kt++) {
                const int cb = kt & 1;
                if (kt < 7) {
                    #pragma unroll
                    for (int q = 0; q < 8; q++)
                        wb[cb ^ 1][q] = *(const bf16x8*)(W0h + bo8[q] + (kt + 1) * 1024);
                }
                #pragma unroll
                for (int q = 0; q < 8; q++)
                    acc[q] = __builtin_amdgcn_mfma_f32_16x16x32_bf16(af[kt], wb[cb][q], acc[q], 0, 0, 0);
            }
        }
        __syncthreads(); // bar3: xb(t) ready (phase C done)

        // ---- A2: acc += x(t) @ W_ih0^T (all LDS) ----
        {
            bf16x8 ax = *(const bf16x8*)xA;
            #pragma unroll
            for (int q = 0; q < 8; q++) {
                bf16x8 bx = *(const bf16x8*)(wxs_c + bo1[q]);
                acc[q] = __builtin_amdgcn_mfma_f32_16x16x32_bf16(ax, bx, acc[q], 0, 0, 0);
            }
        }
        // ---- EW-A: c0,h0 update -> h0b[p^1] ----
        #pragma unroll
        for (int h = 0; h < 2; h++) {
            #pragma unroll
            for (int r = 0; r < 4; r++) {
                float iv = acc[0 + h][r], fv = acc[2 + h][r], gv = acc[4 + h][r], ov = acc[6 + h][r];
                float cn = sigf(fv) * c0r[h][r] + sigf(iv) * tanhfast(gv);
                float hn = sigf(ov) * tanhfast(cn);
                c0r[h][r] = cn;
                h0b[p ^ 1][lq * 4 + r][wv * 32 + h * 16 + l15] = __float2bfloat16(hn);
            }
        }
        __syncthreads(); // bar1: h0_new visible

        // ---- B: acc = bias1 + h0_new @ W1x^T + h1_old @ W1h^T (fused 16-group, depth-1 prefetch) ----
        #pragma unroll
        for (int q = 0; q < 8; q++) { f32x4 v = {bs1[q], bs1[q], bs1[q], bs1[q]}; acc[q] = v; }
        {
            const char* base1 = hA + (p ^ 1) * 8448 + aoff;
            const char* base2 = hB + p * 8448 + aoff;
            bf16x8 af[16];
            #pragma unroll
            for (int kt = 0; kt < 8; kt++) {
                af[kt]     = *(const bf16x8*)(base1 + kt * 64);
                af[8 + kt] = *(const bf16x8*)(base2 + kt * 64);
            }
            bf16x8 wb[2][8];
            #pragma unroll
            for (int q = 0; q < 8; q++) wb[0][q] = *(const bf16x8*)(W1x + bo8[q]);
            #pragma unroll
            for (int s = 0; s < 16; s++) {
                const int cb = s & 1;
                if (s < 15) {
                    const int ns = s + 1;
                    const char* wsrc = (ns < 8) ? (W1x + ns * 1024) : (W1h + (ns - 8) * 1024);
                    #pragma unroll
                    for (int q = 0; q < 8; q++)
                        wb[cb ^ 1][q] = *(const bf16x8*)(wsrc + bo8[q]);
                }
                #pragma unroll
                for (int q = 0; q < 8; q++)
                    acc[q] = __builtin_amdgcn_mfma_f32_16x16x32_bf16(af[s], wb[cb][q], acc[q], 0, 0, 0);
            }
        }
        // ---- EW-B -> h1b[p^1] ----
        #pragma unroll
        for (int h = 0; h < 2; h++) {
            #pragma unroll
            for (int r = 0; r < 4; r++) {
                float iv = acc[0 + h][r], fv = acc[2 + h][r], gv = acc[4 + h][r], ov = acc[6 + h][r];
                float cn = sigf(fv) * c1r[h][r] + sigf(iv) * tanhfast(gv);
                float hn = sigf(ov) * tanhfast(cn);
                c1r[h][r] = cn;
                h1b[p ^ 1][lq * 4 + r][wv * 32 + h * 16 + l15] = __float2bfloat16(hn);
            }
        }
        __syncthreads(); // bar2: h1_new visible
    }

    // final output step: y(TT-1); h1(TT-1) is in h1b[TT & 1]
    if (wv == 7) phaseC(TT);
}

extern "C" void kernel_launch(void* const* d_in, const int* in_sizes, int n_in,
                              void* d_out, int out_size, void* d_ws, size_t ws_size,
                              hipStream_t stream) {
    const float* z      = (const float*)d_in[0];
    const float* w_lh   = (const float*)d_in[3];
    const float* b_lh   = (const float*)d_in[4];
    const float* w_lc   = (const float*)d_in[5];
    const float* b_lc   = (const float*)d_in[6];
    const float* w_ih0  = (const float*)d_in[7];
    const float* w_hh0  = (const float*)d_in[8];
    const float* b_ih0  = (const float*)d_in[9];
    const float* b_hh0  = (const float*)d_in[10];
    const float* w_ih1  = (const float*)d_in[11];
    const float* w_hh1  = (const float*)d_in[12];
    const float* b_ih1  = (const float*)d_in[13];
    const float* b_hh1  = (const float*)d_in[14];
    const float* w_proj = (const float*)d_in[15];
    const float* b_proj = (const float*)d_in[16];
    char* ws = (char*)d_ws;
    float* out = (float*)d_out;

    prep_kernel<<<3240, 256, 0, stream>>>(w_ih0, w_hh0, w_ih1, w_hh1, w_proj,
                                          b_ih0, b_hh0, b_ih1, b_hh1, ws);
    decoder_kernel<<<NBLK, 512, 0, stream>>>(z, w_lh, b_lh, w_lc, b_lc, b_proj, ws, out);
}

// Round 4
// 28901.538 us; speedup vs baseline: 1.2535x; 1.2535x over previous
//
#include <hip/hip_runtime.h>
#include <hip/hip_bf16.h>

#define NB 16
#define NBLK 128
#define TT 512
#define DD 20

using bf16x8 = __attribute__((ext_vector_type(8))) short;
using f32x4  = __attribute__((ext_vector_type(4))) float;

typedef __attribute__((address_space(3))) unsigned int lds_uint;
typedef __attribute__((address_space(1))) unsigned int glob_uint;

// workspace byte offsets (prep output)
#define OFF_WIH0  0          // 1024x20  -> 64 tiles x 1 kt
#define OFF_WHH0  65536      // 1024x256 -> 64 x 8
#define OFF_WIH1  589824
#define OFF_WHH1  1114112
#define OFF_WPROJ 1638400    // 20x256 -> 2 x 8
#define OFF_B0    1654784
#define OFF_B1    1658880

// smem layout (bytes)
#define SM_STG   0        // 8 waves * 3 bufs * 4096 = 98304 (cinit 64K + zb 2K overlay during init)
#define SM_H0    98304    // 2*16*264*2 = 16896
#define SM_H1    115200   // 16896
#define SM_XB    132096   // 1024
#define SM_WPS   133120   // 16384
#define SM_TOTAL 149504

__device__ __forceinline__ float sigf(float x) { return 1.0f / (1.0f + __expf(-x)); }
__device__ __forceinline__ float tanhfast(float x) { return 1.0f - 2.0f / (__expf(2.0f * x) + 1.0f); }

__device__ __forceinline__ void stage16(const char* g, const char* l) {
    __builtin_amdgcn_global_load_lds((glob_uint*)g, (lds_uint*)l, 16, 0, 0);
}
__device__ __forceinline__ void waitvm(int n) {   // n is compile-time after unroll
    if (n >= 8)      asm volatile("s_waitcnt vmcnt(8)" ::: "memory");
    else if (n >= 4) asm volatile("s_waitcnt vmcnt(4)" ::: "memory");
    else             asm volatile("s_waitcnt vmcnt(0)" ::: "memory");
}

// ---- prep: fp32 weights -> bf16, swizzled into MFMA B-fragment order ----
__global__ void prep_kernel(const float* __restrict__ wih0, const float* __restrict__ whh0,
                            const float* __restrict__ wih1, const float* __restrict__ whh1,
                            const float* __restrict__ wproj,
                            const float* __restrict__ bih0, const float* __restrict__ bhh0,
                            const float* __restrict__ bih1, const float* __restrict__ bhh1,
                            char* __restrict__ ws) {
    int idx = blockIdx.x * 256 + threadIdx.x;
    const float* src;
    __hip_bfloat16* dst;
    int e, N, K, nKt;
    if (idx < 32768)       { e = idx;          src = wih0;  N = 1024; K = 20;  nKt = 1; dst = (__hip_bfloat16*)(ws + OFF_WIH0); }
    else if (idx < 294912) { e = idx - 32768;  src = whh0;  N = 1024; K = 256; nKt = 8; dst = (__hip_bfloat16*)(ws + OFF_WHH0); }
    else if (idx < 557056) { e = idx - 294912; src = wih1;  N = 1024; K = 256; nKt = 8; dst = (__hip_bfloat16*)(ws + OFF_WIH1); }
    else if (idx < 819200) { e = idx - 557056; src = whh1;  N = 1024; K = 256; nKt = 8; dst = (__hip_bfloat16*)(ws + OFF_WHH1); }
    else if (idx < 827392) { e = idx - 819200; src = wproj; N = 20;   K = 256; nKt = 8; dst = (__hip_bfloat16*)(ws + OFF_WPROJ); }
    else if (idx < 828416) { int j = idx - 827392; ((float*)(ws + OFF_B0))[j] = bih0[j] + bhh0[j]; return; }
    else if (idx < 829440) { int j = idx - 828416; ((float*)(ws + OFF_B1))[j] = bih1[j] + bhh1[j]; return; }
    else return;
    int j    = e & 7;
    int lane = (e >> 3) & 63;
    int tile = e >> 9;
    int kt = tile % nKt;
    int nt = tile / nKt;
    int n = nt * 16 + (lane & 15);
    int k = kt * 32 + ((lane >> 4) << 3) + j;
    float v = (n < N && k < K) ? src[n * K + k] : 0.0f;
    dst[e] = __float2bfloat16(v);
}

// ---- persistent decoder: 128 blocks x 512 threads, 16 batch rows/block, 512 steps ----
__global__ __launch_bounds__(512, 1) void decoder_kernel(
    const float* __restrict__ z, const float* __restrict__ w_lh, const float* __restrict__ b_lh,
    const float* __restrict__ w_lc, const float* __restrict__ b_lc,
    const float* __restrict__ b_proj, const char* __restrict__ ws,
    float* __restrict__ out) {

    __shared__ __align__(16) char smem[SM_TOTAL];

    const int tid = threadIdx.x;
    const int b0  = blockIdx.x * NB;

    __hip_bfloat16* h0p = (__hip_bfloat16*)(smem + SM_H0); // [ping*4224 + b*264 + col]
    __hip_bfloat16* h1p = (__hip_bfloat16*)(smem + SM_H1);
    __hip_bfloat16* xbh = (__hip_bfloat16*)(smem + SM_XB); // [16][32]
    float* cinitf = (float*)smem;                          // overlay: [2*16*256]
    float* zbf    = (float*)(smem + 65536);                // overlay: [16*32]

    // stage z, zero x0 (512 threads cover 16*32)
    zbf[tid] = z[(b0 + (tid >> 5)) * 32 + (tid & 31)];
    xbh[tid] = __float2bfloat16(0.0f);
    // stage W_proj into LDS (resident)
    {
        const bf16x8* sp = (const bf16x8*)(ws + OFF_WPROJ);
        bf16x8* dp = (bf16x8*)(smem + SM_WPS);
        for (int i = tid; i < 1024; i += 512) dp[i] = sp[i];
    }
    __syncthreads();

    // h/c init (fp32 VALU, K=32)
    for (int ii = 0; ii < 16; ii++) {
        int pi = ii * 512 + tid;
        int b = pi >> 9, col = pi & 511;
        float dh = b_lh[col], dc = b_lc[col];
        #pragma unroll 8
        for (int k = 0; k < 32; k++) {
            float zv = zbf[b * 32 + k];
            dh += zv * w_lh[col * 32 + k];
            dc += zv * w_lc[col * 32 + k];
        }
        if (col < 256) { h0p[b * 264 + col]         = __float2bfloat16(dh); cinitf[b * 256 + col]          = dc; }
        else           { h1p[b * 264 + (col - 256)] = __float2bfloat16(dh); cinitf[4096 + b * 256 + col - 256] = dc; }
    }
    __syncthreads();

    const int wv = tid >> 6, ln = tid & 63;
    const int l15 = ln & 15, lq = ln >> 4;
    const int lnoff = ln * 16;

    float c0r[2][4], c1r[2][4];
    #pragma unroll
    for (int h = 0; h < 2; h++)
        #pragma unroll
        for (int r = 0; r < 4; r++) {
            int u = wv * 32 + h * 16 + l15, b = lq * 4 + r;
            c0r[h][r] = cinitf[b * 256 + u];
            c1r[h][r] = cinitf[4096 + b * 256 + u];
        }

    const float* bias0 = (const float*)(ws + OFF_B0);
    const float* bias1 = (const float*)(ws + OFF_B1);
    float bs0[8], bs1[8];
    #pragma unroll
    for (int q = 0; q < 8; q++) {
        int col = (q >> 1) * 256 + wv * 32 + (q & 1) * 16 + l15;
        bs0[q] = bias0[col];
        bs1[q] = bias1[col];
    }
    const float bpj0 = b_proj[l15];
    const float bpj1 = (l15 < 4) ? b_proj[16 + l15] : 0.0f;

    int bo8[8], bo1[8];
    #pragma unroll
    for (int q = 0; q < 8; q++) {
        int tbq = (q >> 1) * 16 + wv * 2 + (q & 1);
        bo8[q] = tbq * 8192 + lnoff;
        bo1[q] = tbq * 1024 + lnoff;
    }

    const char* W0x = ws + OFF_WIH0;
    const char* W0h = ws + OFF_WHH0;
    const char* W1x = ws + OFF_WIH1;
    const char* W1h = ws + OFF_WHH1;
    const char* wps_c = smem + SM_WPS;

    const char* hA = smem + SM_H0;
    const char* hB = smem + SM_H1;
    const int aoff = l15 * 528 + lq * 16;
    const char* xA = smem + SM_XB + l15 * 64 + lq * 16;
    char* mystg = smem + SM_STG + wv * 12288;

    float* outp = out + (size_t)b0 * TT * DD;

    __syncthreads(); // protect cinit/zb overlay before first DMA into staging area

    // phase C: emits y(t-1) -> out, x(t) -> xb. h1(t-1) lives in h1b[t&1]. Pure LDS + stores.
    auto phaseC = [&](int t) {
        const int pp = t & 1;
        f32x4 py0 = {bpj0, bpj0, bpj0, bpj0};
        f32x4 py1 = {bpj1, bpj1, bpj1, bpj1};
        const char* baseh = hB + pp * 8448 + aoff;
        #pragma unroll
        for (int kt = 0; kt < 8; kt++) {
            bf16x8 ah  = *(const bf16x8*)(baseh + kt * 64);
            bf16x8 bf0 = *(const bf16x8*)(wps_c + kt * 1024 + lnoff);
            bf16x8 bf1 = *(const bf16x8*)(wps_c + 8192 + kt * 1024 + lnoff);
            py0 = __builtin_amdgcn_mfma_f32_16x16x32_bf16(ah, bf0, py0, 0, 0, 0);
            py1 = __builtin_amdgcn_mfma_f32_16x16x32_bf16(ah, bf1, py1, 0, 0, 0);
        }
        #pragma unroll
        for (int r = 0; r < 4; r++) {
            int b = lq * 4 + r;
            float y0 = py0[r];
            outp[(size_t)(b * TT + (t - 1)) * DD + l15] = y0;
            xbh[b * 32 + l15] = __float2bfloat16(y0);
            if (l15 < 4) {
                float y1 = py1[r];
                outp[(size_t)(b * TT + (t - 1)) * DD + 16 + l15] = y1;
                xbh[b * 32 + 16 + l15] = __float2bfloat16(y1);
            }
        }
        // drain stores so they never pollute this wave's vmcnt chunk pacing
        asm volatile("s_waitcnt vmcnt(0)" ::: "memory");
    };

    #pragma unroll 1
    for (int t = 0; t < TT; t++) {
        const int p = t & 1;

        // ---- phase A: stage prologue (chunks 0..2 of W0h) ----
        #pragma unroll
        for (int c = 0; c < 3; c++) {
            const int q0 = (c & 1) * 4, kt = c >> 1;
            #pragma unroll
            for (int j = 0; j < 4; j++)
                stage16(W0h + bo8[q0 + j] + kt * 1024, mystg + c * 4096 + j * 1024);
        }

        // phase C(t-1) on wave 7, overlapped with other waves' A-loop
        if (t > 0 && wv == 7) phaseC(t);

        // ---- A-loop: acc = bias0 + h0_old @ W0h^T; chunks 16,17 = W0x prefetch ----
        f32x4 acc[8];
        #pragma unroll
        for (int q = 0; q < 8; q++) { f32x4 v = {bs0[q], bs0[q], bs0[q], bs0[q]}; acc[q] = v; }
        {
            const char* baseA = hA + p * 8448 + aoff;
            #pragma unroll
            for (int c = 0; c < 16; c++) {
                waitvm(8);
                const int q0 = (c & 1) * 4, kt = c >> 1, bf_ = c % 3;
                bf16x8 af = *(const bf16x8*)(baseA + kt * 64);
                bf16x8 w0 = *(const bf16x8*)(mystg + bf_ * 4096 + 0 * 1024 + lnoff);
                bf16x8 w1 = *(const bf16x8*)(mystg + bf_ * 4096 + 1 * 1024 + lnoff);
                bf16x8 w2 = *(const bf16x8*)(mystg + bf_ * 4096 + 2 * 1024 + lnoff);
                bf16x8 w3 = *(const bf16x8*)(mystg + bf_ * 4096 + 3 * 1024 + lnoff);
                acc[q0 + 0] = __builtin_amdgcn_mfma_f32_16x16x32_bf16(af, w0, acc[q0 + 0], 0, 0, 0);
                acc[q0 + 1] = __builtin_amdgcn_mfma_f32_16x16x32_bf16(af, w1, acc[q0 + 1], 0, 0, 0);
                acc[q0 + 2] = __builtin_amdgcn_mfma_f32_16x16x32_bf16(af, w2, acc[q0 + 2], 0, 0, 0);
                acc[q0 + 3] = __builtin_amdgcn_mfma_f32_16x16x32_bf16(af, w3, acc[q0 + 3], 0, 0, 0);
                asm volatile("s_waitcnt lgkmcnt(0)" ::: "memory"); // buffer reads done before refill
                const int cn = c + 3;
                if (cn < 18) {
                    const int nq0 = (cn & 1) * 4, nb = cn % 3;
                    if (cn < 16) {
                        const int ktn = cn >> 1;
                        #pragma unroll
                        for (int j = 0; j < 4; j++)
                            stage16(W0h + bo8[nq0 + j] + ktn * 1024, mystg + nb * 4096 + j * 1024);
                    } else {
                        #pragma unroll
                        for (int j = 0; j < 4; j++)
                            stage16(W0x + bo1[nq0 + j], mystg + nb * 4096 + j * 1024);
                    }
                }
            }
        }
        __syncthreads(); // bar3: drains W0x chunks; xb(t) from phase C ready

        // ---- A2: acc += x(t) @ W_ih0^T (staged in bufs 1,2) ----
        {
            bf16x8 ax = *(const bf16x8*)xA;
            #pragma unroll
            for (int q = 0; q < 4; q++) {
                bf16x8 w = *(const bf16x8*)(mystg + 1 * 4096 + q * 1024 + lnoff);
                acc[q] = __builtin_amdgcn_mfma_f32_16x16x32_bf16(ax, w, acc[q], 0, 0, 0);
            }
            #pragma unroll
            for (int q = 0; q < 4; q++) {
                bf16x8 w = *(const bf16x8*)(mystg + 2 * 4096 + q * 1024 + lnoff);
                acc[4 + q] = __builtin_amdgcn_mfma_f32_16x16x32_bf16(ax, w, acc[4 + q], 0, 0, 0);
            }
        }
        // ---- EW-A: c0,h0 update -> h0b[p^1] ----
        #pragma unroll
        for (int h = 0; h < 2; h++) {
            #pragma unroll
            for (int r = 0; r < 4; r++) {
                float iv = acc[0 + h][r], fv = acc[2 + h][r], gv = acc[4 + h][r], ov = acc[6 + h][r];
                float cn = sigf(fv) * c0r[h][r] + sigf(iv) * tanhfast(gv);
                float hn = sigf(ov) * tanhfast(cn);
                c0r[h][r] = cn;
                h0p[(p ^ 1) * 4224 + (lq * 4 + r) * 264 + wv * 32 + h * 16 + l15] = __float2bfloat16(hn);
            }
        }
        __syncthreads(); // bar1: h0_new visible

        // ---- phase B: acc = bias1 + h0_new @ W1x^T + h1_old @ W1h^T (32 chunks) ----
        #pragma unroll
        for (int q = 0; q < 8; q++) { f32x4 v = {bs1[q], bs1[q], bs1[q], bs1[q]}; acc[q] = v; }
        {
            const char* base1 = hA + (p ^ 1) * 8448 + aoff;
            const char* base2 = hB + p * 8448 + aoff;
            #pragma unroll
            for (int c = 0; c < 3; c++) {
                const int q0 = (c & 1) * 4, kt = c >> 1;
                #pragma unroll
                for (int j = 0; j < 4; j++)
                    stage16(W1x + bo8[q0 + j] + kt * 1024, mystg + c * 4096 + j * 1024);
            }
            #pragma unroll
            for (int c = 0; c < 32; c++) {
                waitvm(c <= 29 ? 8 : (c == 30 ? 4 : 0));
                const int q0 = (c & 1) * 4, kt = (c & 15) >> 1, bf_ = c % 3;
                const char* ab = (c < 16) ? base1 : base2;
                bf16x8 af = *(const bf16x8*)(ab + kt * 64);
                bf16x8 w0 = *(const bf16x8*)(mystg + bf_ * 4096 + 0 * 1024 + lnoff);
                bf16x8 w1 = *(const bf16x8*)(mystg + bf_ * 4096 + 1 * 1024 + lnoff);
                bf16x8 w2 = *(const bf16x8*)(mystg + bf_ * 4096 + 2 * 1024 + lnoff);
                bf16x8 w3 = *(const bf16x8*)(mystg + bf_ * 4096 + 3 * 1024 + lnoff);
                acc[q0 + 0] = __builtin_amdgcn_mfma_f32_16x16x32_bf16(af, w0, acc[q0 + 0], 0, 0, 0);
                acc[q0 + 1] = __builtin_amdgcn_mfma_f32_16x16x32_bf16(af, w1, acc[q0 + 1], 0, 0, 0);
                acc[q0 + 2] = __builtin_amdgcn_mfma_f32_16x16x32_bf16(af, w2, acc[q0 + 2], 0, 0, 0);
                acc[q0 + 3] = __builtin_amdgcn_mfma_f32_16x16x32_bf16(af, w3, acc[q0 + 3], 0, 0, 0);
                asm volatile("s_waitcnt lgkmcnt(0)" ::: "memory");
                const int cn = c + 3;
                if (cn < 32) {
                    const int nq0 = (cn & 1) * 4, nb = cn % 3, ktn = (cn & 15) >> 1;
                    const char* wsrc = (cn < 16) ? W1x : W1h;
                    #pragma unroll
                    for (int j = 0; j < 4; j++)
                        stage16(wsrc + bo8[nq0 + j] + ktn * 1024, mystg + nb * 4096 + j * 1024);
                }
            }
        }
        // ---- EW-B -> h1b[p^1] ----
        #pragma unroll
        for (int h = 0; h < 2; h++) {
            #pragma unroll
            for (int r = 0; r < 4; r++) {
                float iv = acc[0 + h][r], fv = acc[2 + h][r], gv = acc[4 + h][r], ov = acc[6 + h][r];
                float cn = sigf(fv) * c1r[h][r] + sigf(iv) * tanhfast(gv);
                float hn = sigf(ov) * tanhfast(cn);
                c1r[h][r] = cn;
                h1p[(p ^ 1) * 4224 + (lq * 4 + r) * 264 + wv * 32 + h * 16 + l15] = __float2bfloat16(hn);
            }
        }
        __syncthreads(); // bar2: h1_new visible
    }

    // final output: y(TT-1); h1(TT-1) is in h1b[TT & 1]
    if (wv == 7) phaseC(TT);
}

extern "C" void kernel_launch(void* const* d_in, const int* in_sizes, int n_in,
                              void* d_out, int out_size, void* d_ws, size_t ws_size,
                              hipStream_t stream) {
    const float* z      = (const float*)d_in[0];
    const float* w_lh   = (const float*)d_in[3];
    const float* b_lh   = (const float*)d_in[4];
    const float* w_lc   = (const float*)d_in[5];
    const float* b_lc   = (const float*)d_in[6];
    const float* w_ih0  = (const float*)d_in[7];
    const float* w_hh0  = (const float*)d_in[8];
    const float* b_ih0  = (const float*)d_in[9];
    const float* b_hh0  = (const float*)d_in[10];
    const float* w_ih1  = (const float*)d_in[11];
    const float* w_hh1  = (const float*)d_in[12];
    const float* b_ih1  = (const float*)d_in[13];
    const float* b_hh1  = (const float*)d_in[14];
    const float* w_proj = (const float*)d_in[15];
    const float* b_proj = (const float*)d_in[16];
    char* ws = (char*)d_ws;
    float* out = (float*)d_out;

    prep_kernel<<<3240, 256, 0, stream>>>(w_ih0, w_hh0, w_ih1, w_hh1, w_proj,
                                          b_ih0, b_hh0, b_ih1, b_hh1, ws);
    decoder_kernel<<<NBLK, 512, 0, stream>>>(z, w_lh, b_lh, w_lc, b_lc, b_proj, ws, out);
}

// Round 5
// 14722.313 us; speedup vs baseline: 2.4608x; 1.9631x over previous
//
#include <hip/hip_runtime.h>
#include <hip/hip_bf16.h>

#define NB 32
#define NBLK 64
#define TT 512
#define DD 20

using bf16x8 = __attribute__((ext_vector_type(8))) short;
using f32x4  = __attribute__((ext_vector_type(4))) float;

typedef __attribute__((address_space(3))) unsigned int lds_uint;
typedef __attribute__((address_space(1))) unsigned int glob_uint;

// workspace byte offsets (prep output)
#define OFF_WIH0  0          // 1024x20  -> 64 tiles x 1 kt (stride 1024)
#define OFF_WHH0  65536      // 1024x256 -> 64 tiles x 8 kt (stride 8192)
#define OFF_WIH1  589824
#define OFF_WHH1  1114112
#define OFF_WPROJ 1638400    // 20x256 -> 2 tiles x 8 kt
#define OFF_B0    1654784
#define OFF_B1    1658880

// smem layout (bytes)
#define SM_PAN   0        // 2 panels x 32768 (cinit 64K overlay during init)
#define SM_H0    65536    // 32*264*2 = 16896 (single copy, in-place)
#define SM_H1    82432    // 16896
#define SM_XB    99328    // 32*32*2 = 2048
#define SM_WPS   101376   // 16384 (resident)
#define SM_ZB    117760   // 4096
#define SM_TOTAL 121856

__device__ __forceinline__ float sigf(float x) { return 1.0f / (1.0f + __expf(-x)); }
__device__ __forceinline__ float tanhfast(float x) { return 1.0f - 2.0f / (__expf(2.0f * x) + 1.0f); }

__device__ __forceinline__ void stage16(const char* g, const char* l) {
    __builtin_amdgcn_global_load_lds((glob_uint*)g, (lds_uint*)l, 16, 0, 0);
}

// ---- prep: fp32 weights -> bf16, swizzled into MFMA B-fragment order ----
__global__ void prep_kernel(const float* __restrict__ wih0, const float* __restrict__ whh0,
                            const float* __restrict__ wih1, const float* __restrict__ whh1,
                            const float* __restrict__ wproj,
                            const float* __restrict__ bih0, const float* __restrict__ bhh0,
                            const float* __restrict__ bih1, const float* __restrict__ bhh1,
                            char* __restrict__ ws) {
    int idx = blockIdx.x * 256 + threadIdx.x;
    const float* src;
    __hip_bfloat16* dst;
    int e, N, K, nKt;
    if (idx < 32768)       { e = idx;          src = wih0;  N = 1024; K = 20;  nKt = 1; dst = (__hip_bfloat16*)(ws + OFF_WIH0); }
    else if (idx < 294912) { e = idx - 32768;  src = whh0;  N = 1024; K = 256; nKt = 8; dst = (__hip_bfloat16*)(ws + OFF_WHH0); }
    else if (idx < 557056) { e = idx - 294912; src = wih1;  N = 1024; K = 256; nKt = 8; dst = (__hip_bfloat16*)(ws + OFF_WIH1); }
    else if (idx < 819200) { e = idx - 557056; src = whh1;  N = 1024; K = 256; nKt = 8; dst = (__hip_bfloat16*)(ws + OFF_WHH1); }
    else if (idx < 827392) { e = idx - 819200; src = wproj; N = 20;   K = 256; nKt = 8; dst = (__hip_bfloat16*)(ws + OFF_WPROJ); }
    else if (idx < 828416) { int j = idx - 827392; ((float*)(ws + OFF_B0))[j] = bih0[j] + bhh0[j]; return; }
    else if (idx < 829440) { int j = idx - 828416; ((float*)(ws + OFF_B1))[j] = bih1[j] + bhh1[j]; return; }
    else return;
    int j    = e & 7;
    int lane = (e >> 3) & 63;
    int tile = e >> 9;
    int kt = tile % nKt;
    int nt = tile / nKt;
    int n = nt * 16 + (lane & 15);
    int k = kt * 32 + ((lane >> 4) << 3) + j;
    float v = (n < N && k < K) ? src[n * K + k] : 0.0f;
    dst[e] = __float2bfloat16(v);
}

// ---- persistent decoder: 64 blocks x 512 threads, 32 batch rows/block, 512 steps ----
__global__ __launch_bounds__(512, 1) void decoder_kernel(
    const float* __restrict__ z, const float* __restrict__ w_lh, const float* __restrict__ b_lh,
    const float* __restrict__ w_lc, const float* __restrict__ b_lc,
    const float* __restrict__ b_proj, const char* __restrict__ ws,
    float* __restrict__ out) {

    __shared__ __align__(16) char smem[SM_TOTAL];

    const int tid = threadIdx.x;
    const int b0  = blockIdx.x * NB;

    __hip_bfloat16* h0p = (__hip_bfloat16*)(smem + SM_H0); // [m*264 + u]
    __hip_bfloat16* h1p = (__hip_bfloat16*)(smem + SM_H1);
    __hip_bfloat16* xbh = (__hip_bfloat16*)(smem + SM_XB); // [32][32]

    // ---- init: stage z, zero xb, stage W_proj ----
    {
        float* zbf = (float*)(smem + SM_ZB);
        zbf[tid]       = z[(b0 + (tid >> 5)) * 32 + (tid & 31)];
        int i2 = tid + 512;
        zbf[i2]        = z[(b0 + (i2 >> 5)) * 32 + (i2 & 31)];
        ((unsigned int*)(smem + SM_XB))[tid] = 0;  // 2048 B of zeros
        const bf16x8* sp = (const bf16x8*)(ws + OFF_WPROJ);
        bf16x8* dp = (bf16x8*)(smem + SM_WPS);
        dp[tid] = sp[tid];
        dp[tid + 512] = sp[tid + 512];
    }
    __syncthreads();

    // ---- h/c init (fp32 VALU, K=32): 32 rows x 512 cols ----
    {
        float* cinitf = (float*)smem;            // overlay in panel area: [2][32][256]
        const float* zbf = (const float*)(smem + SM_ZB);
        for (int ii = 0; ii < 32; ii++) {
            int pi = ii * 512 + tid;
            int b = pi >> 9, col = pi & 511;
            float dh = b_lh[col], dc = b_lc[col];
            #pragma unroll 8
            for (int k = 0; k < 32; k++) {
                float zv = zbf[b * 32 + k];
                dh += zv * w_lh[col * 32 + k];
                dc += zv * w_lc[col * 32 + k];
            }
            if (col < 256) { h0p[b * 264 + col]         = __float2bfloat16(dh); cinitf[b * 256 + col]                 = dc; }
            else           { h1p[b * 264 + (col - 256)] = __float2bfloat16(dh); cinitf[8192 + b * 256 + (col - 256)] = dc; }
        }
    }
    __syncthreads();

    const int wv = tid >> 6, ln = tid & 63;
    const int l15 = ln & 15, lq = ln >> 4;
    const int lnoff = ln * 16;

    // c-state lane-local: m = mt*16 + lq*4 + r, u = wv*32 + h*16 + l15
    float c0r[2][2][4], c1r[2][2][4];
    {
        const float* cinitf = (const float*)smem;
        #pragma unroll
        for (int mt = 0; mt < 2; mt++)
            #pragma unroll
            for (int h = 0; h < 2; h++)
                #pragma unroll
                for (int r = 0; r < 4; r++) {
                    int m = mt * 16 + lq * 4 + r, u = wv * 32 + h * 16 + l15;
                    c0r[mt][h][r] = cinitf[m * 256 + u];
                    c1r[mt][h][r] = cinitf[8192 + m * 256 + u];
                }
    }
    __syncthreads(); // cinit overlay dead; panel staging may now write

    const float* bias0 = (const float*)(ws + OFF_B0);
    const float* bias1 = (const float*)(ws + OFF_B1);
    float bs0[8], bs1[8];
    #pragma unroll
    for (int q = 0; q < 8; q++) {
        int col = (q >> 1) * 256 + wv * 32 + (q & 1) * 16 + l15;
        bs0[q] = bias0[col];
        bs1[q] = bias1[col];
    }
    // phase-C assignment: waves 0..3 -> (mt = wv>>1, nt = wv&1)
    const int pc_nt = wv & 1, pc_mt = wv >> 1;
    const int pc_col = pc_nt * 16 + l15;
    const float bpj = (wv < 4 && pc_col < 20) ? b_proj[pc_col] : 0.0f;

    const char* W0x = ws + OFF_WIH0;
    const char* W0h = ws + OFF_WHH0;
    const char* W1x = ws + OFF_WIH1;
    const char* W1h = ws + OFF_WHH1;
    const char* wps_c = smem + SM_WPS;
    const char* h0c = smem + SM_H0;
    const char* h1c = smem + SM_H1;
    const char* xbc = smem + SM_XB;

    float* outp = out;

    // stage one 32KB panel: tiles [half*32 .. half*32+31] at kt; wave wv stages tiles wv*4..wv*4+3
    auto stagePanel = [&](const char* Wb, int stride, int kt, int half, int buf) {
        const char* gsrc = Wb + (half * 32 + wv * 4) * stride + kt * 1024 + lnoff;
        char* ldst = smem + SM_PAN + buf * 32768 + (wv * 4) * 1024;
        #pragma unroll
        for (int j = 0; j < 4; j++)
            stage16(gsrc + j * stride, ldst + j * 1024);
    };

    f32x4 acc[8][2];

    // compute one panel: q = half*4 + qq, both m-tiles
    auto panelCompute = [&](int buf, int kt, int half, const char* hsrc, bool isX) {
        const char* pb = smem + SM_PAN + buf * 32768;
        bf16x8 af0, af1;
        if (isX) {
            af0 = *(const bf16x8*)(xbc + l15 * 64 + lq * 16);
            af1 = *(const bf16x8*)(xbc + (16 + l15) * 64 + lq * 16);
        } else {
            af0 = *(const bf16x8*)(hsrc + l15 * 528 + kt * 64 + lq * 16);
            af1 = *(const bf16x8*)(hsrc + (16 + l15) * 528 + kt * 64 + lq * 16);
        }
        #pragma unroll
        for (int qq = 0; qq < 4; qq++) {
            int lt = (qq >> 1) * 16 + wv * 2 + (qq & 1);
            bf16x8 w = *(const bf16x8*)(pb + lt * 1024 + lnoff);
            acc[half * 4 + qq][0] = __builtin_amdgcn_mfma_f32_16x16x32_bf16(af0, w, acc[half * 4 + qq][0], 0, 0, 0);
            acc[half * 4 + qq][1] = __builtin_amdgcn_mfma_f32_16x16x32_bf16(af1, w, acc[half * 4 + qq][1], 0, 0, 0);
        }
    };

    // phase C (waves 0..3): y(t-1) -> out, x(t) -> xb. Reads h1 (state of t-1), wps. Pure LDS.
    auto phaseC = [&](int t) {
        f32x4 py = {bpj, bpj, bpj, bpj};
        #pragma unroll
        for (int kt = 0; kt < 8; kt++) {
            bf16x8 ah = *(const bf16x8*)(h1c + (pc_mt * 16 + l15) * 528 + kt * 64 + lq * 16);
            bf16x8 wf = *(const bf16x8*)(wps_c + pc_nt * 8192 + kt * 1024 + lnoff);
            py = __builtin_amdgcn_mfma_f32_16x16x32_bf16(ah, wf, py, 0, 0, 0);
        }
        if (pc_col < 20) {
            #pragma unroll
            for (int r = 0; r < 4; r++) {
                int row = pc_mt * 16 + lq * 4 + r;
                outp[((size_t)(b0 + row) * TT + (t - 1)) * DD + pc_col] = py[r];
                xbh[row * 32 + pc_col] = __float2bfloat16(py[r]);
            }
        }
    };

    // ---- prologue: stage panel 0 (W0h kt0 half0) into buf0 ----
    stagePanel(W0h, 8192, 0, 0, 0);

    #pragma unroll 1
    for (int t = 0; t < TT; t++) {
        // ======== phase A: gates0 = bias0 + h0 @ W0h^T (+ x @ W0x^T) ========
        #pragma unroll
        for (int q = 0; q < 8; q++) {
            f32x4 v = {bs0[q], bs0[q], bs0[q], bs0[q]};
            acc[q][0] = v; acc[q][1] = v;
        }
        #pragma unroll 2
        for (int s = 0; s < 16; s++) {
            const int kt = s >> 1, half = s & 1;
            if (s < 15) stagePanel(W0h, 8192, (s + 1) >> 1, (s + 1) & 1, (s + 1) & 1);
            else        stagePanel(W0x, 1024, 0, 0, 0);              // s+1 = 16
            if (s == 0 && t > 0 && wv < 4) phaseC(t);
            panelCompute(s & 1, kt, half, h0c, false);
            __syncthreads();
        }
        // A2: panels 16,17 (W0x halves, A = xb)
        stagePanel(W0x, 1024, 0, 1, 1);                              // s+1 = 17
        panelCompute(0, 0, 0, nullptr, true);
        __syncthreads();
        stagePanel(W1x, 8192, 0, 0, 0);                              // s+1 = 18
        panelCompute(1, 0, 1, nullptr, true);
        __syncthreads();

        // ---- EW-A: c0,h0 update (in place) ----
        #pragma unroll
        for (int mt = 0; mt < 2; mt++)
            #pragma unroll
            for (int h = 0; h < 2; h++)
                #pragma unroll
                for (int r = 0; r < 4; r++) {
                    float iv = acc[0 + h][mt][r], fv = acc[2 + h][mt][r];
                    float gv = acc[4 + h][mt][r], ov = acc[6 + h][mt][r];
                    float cn = sigf(fv) * c0r[mt][h][r] + sigf(iv) * tanhfast(gv);
                    float hn = sigf(ov) * tanhfast(cn);
                    c0r[mt][h][r] = cn;
                    h0p[(mt * 16 + lq * 4 + r) * 264 + wv * 32 + h * 16 + l15] = __float2bfloat16(hn);
                }
        __syncthreads();

        // ======== phase B: gates1 = bias1 + h0_new @ W1x^T + h1 @ W1h^T ========
        #pragma unroll
        for (int q = 0; q < 8; q++) {
            f32x4 v = {bs1[q], bs1[q], bs1[q], bs1[q]};
            acc[q][0] = v; acc[q][1] = v;
        }
        #pragma unroll 2
        for (int s = 18; s < 50; s++) {
            const int ss = s - 18;
            const int kt = (ss & 15) >> 1, half = ss & 1;
            const int ns = ss + 1;
            if (ns < 32) stagePanel(ns < 16 ? W1x : W1h, 8192, (ns & 15) >> 1, ns & 1, (s + 1) & 1);
            else         stagePanel(W0h, 8192, 0, 0, 0);             // next step's panel 0 (buf0)
            panelCompute(s & 1, kt, half, ss < 16 ? h0c : h1c, false);
            __syncthreads();
        }

        // ---- EW-B: c1,h1 update (in place) ----
        #pragma unroll
        for (int mt = 0; mt < 2; mt++)
            #pragma unroll
            for (int h = 0; h < 2; h++)
                #pragma unroll
                for (int r = 0; r < 4; r++) {
                    float iv = acc[0 + h][mt][r], fv = acc[2 + h][mt][r];
                    float gv = acc[4 + h][mt][r], ov = acc[6 + h][mt][r];
                    float cn = sigf(fv) * c1r[mt][h][r] + sigf(iv) * tanhfast(gv);
                    float hn = sigf(ov) * tanhfast(cn);
                    c1r[mt][h][r] = cn;
                    h1p[(mt * 16 + lq * 4 + r) * 264 + wv * 32 + h * 16 + l15] = __float2bfloat16(hn);
                }
        __syncthreads();
    }

    // final y(TT-1)
    if (wv < 4) phaseC(TT);
}

extern "C" void kernel_launch(void* const* d_in, const int* in_sizes, int n_in,
                              void* d_out, int out_size, void* d_ws, size_t ws_size,
                              hipStream_t stream) {
    const float* z      = (const float*)d_in[0];
    const float* w_lh   = (const float*)d_in[3];
    const float* b_lh   = (const float*)d_in[4];
    const float* w_lc   = (const float*)d_in[5];
    const float* b_lc   = (const float*)d_in[6];
    const float* w_ih0  = (const float*)d_in[7];
    const float* w_hh0  = (const float*)d_in[8];
    const float* b_ih0  = (const float*)d_in[9];
    const float* b_hh0  = (const float*)d_in[10];
    const float* w_ih1  = (const float*)d_in[11];
    const float* w_hh1  = (const float*)d_in[12];
    const float* b_ih1  = (const float*)d_in[13];
    const float* b_hh1  = (const float*)d_in[14];
    const float* w_proj = (const float*)d_in[15];
    const float* b_proj = (const float*)d_in[16];
    char* ws = (char*)d_ws;
    float* out = (float*)d_out;

    prep_kernel<<<3240, 256, 0, stream>>>(w_ih0, w_hh0, w_ih1, w_hh1, w_proj,
                                          b_ih0, b_hh0, b_ih1, b_hh1, ws);
    decoder_kernel<<<NBLK, 512, 0, stream>>>(z, w_lh, b_lh, w_lc, b_lc, b_proj, ws, out);
}